// Round 7
// baseline (710.859 us; speedup 1.0000x reference)
//
#include <hip/hip_runtime.h>
#include <hip/hip_bf16.h>

// Problem constants (reference: T,B,D,H = 1024,512,128,128)
#define T_STEPS 1024
#define BATCH   512
#define DIM     128
#define G3      384          // 3*H gate rows
#define NCHUNK  (T_STEPS/8)  // 128 chunks of 8 steps

typedef __attribute__((ext_vector_type(8))) short bf16x8;
typedef __attribute__((ext_vector_type(4))) float f32x4;

#define LOG2E  1.44269504f   // r,z gate rows pre-scaled by log2(e)
#define LOG2E2 2.88539008f   // n gate rows pre-scaled by 2*log2(e)

// hbuf row stride in shorts: 128 cols + 32 pad -> chain stride 320B.
// Proven round 4: SQ_LDS_BANK_CONFLICT 16.8M -> 0.
#define HSTRIDE 160

__device__ __forceinline__ short f2bf(float f) {
  unsigned u = __builtin_bit_cast(unsigned, f);
  u += 0x7FFFu + ((u >> 16) & 1u);   // round-to-nearest-even
  return (short)(u >> 16);
}

// LDS-only barrier: drains LDS ops for cross-wave visibility but does NOT
// drain vmcnt -> producer global prefetch stays in flight across steps.
__device__ __forceinline__ void block_sync_lds() {
  asm volatile("s_waitcnt lgkmcnt(0)\n\ts_barrier" ::: "memory");
}

// ---------------------------------------------------------------------------
// Prep: Wc = W_ih @ W1 (bf16), W_hh -> bf16, bc = W_ih @ b1 + b_ih (fp32).
// r/z rows scaled by log2e, n rows by 2*log2e -> gate math uses raw exp2.
// ---------------------------------------------------------------------------
__global__ void prep_kernel(const float* __restrict__ W1, const float* __restrict__ b1,
                            const float* __restrict__ W_ih, const float* __restrict__ W_hh,
                            const float* __restrict__ b_ih, const float* __restrict__ b_hh,
                            short* __restrict__ wc_bf, short* __restrict__ whh_bf,
                            float* __restrict__ bc, float* __restrict__ bhh_s) {
  const int g = blockIdx.x;
  const int d = threadIdx.x;
  const float sg = (g < 256) ? LOG2E : LOG2E2;
  float acc = 0.f;
  #pragma unroll 4
  for (int k = 0; k < 128; ++k)
    acc = fmaf(W_ih[g * 128 + k], W1[k * 128 + d], acc);
  wc_bf[g * 128 + d]  = f2bf(acc * sg);
  whh_bf[g * 128 + d] = f2bf(W_hh[g * 128 + d] * sg);

  __shared__ float red[128];
  red[d] = W_ih[g * 128 + d] * b1[d];
  __syncthreads();
  #pragma unroll
  for (int s = 64; s > 0; s >>= 1) {
    if (d < s) red[d] += red[d + s];
    __syncthreads();
  }
  if (d == 0) {
    bc[g]    = (red[0] + b_ih[g]) * sg;
    bhh_s[g] = b_hh[g] * sg;
  }
}

// ---------------------------------------------------------------------------
// Main GRU kernel. 256 blocks (2 chains) x 512 threads (8 waves, 2/SIMD).
// Waves 0-3 = CONSUMERS (24 MFMA/step each); waves 4-7 = PRODUCERS (gi for
// chunk c+1, leveled 4 MFMA/step + 8 f2bf/step).
//
// DEPTH-1 SPLIT-K: all 24 consumer MFMAs are INDEPENDENT (one partial
// accumulator per (gate, col-half, kt)); the 4 K-partials are summed by 3
// VALU adds in the tail. Tests the L~200-250cy MFMA-result-latency theory:
// depth-2 chains stalled at the first dependent (233cy head->dep gap < L);
// depth-1 removes every in-window stall and lands r-partials ~130cy earlier
// so the rg/nv trans chain overlaps the tail of the issue window. Issue
// order r -> n -> z = tail consumption order.
//
// gi PROTOCOL (race lesson, round 6): gcur is read at CHUNK TOP from the
// current chunk's buffer (published before the chunk-boundary barrier) and
// gnext prefetch is guarded to s<7 (same buffer). NEVER read the other
// double-buffer half inside a step: the producer publishes it at s==7 and
// only the following barrier orders that publish.
// mfma_f32_16x16x32_bf16 layouts (m89-verified):
//   A[m=lane&15][k=quad*8+j], B[k=quad*8+j][n=lane&15], D: col=lane&15,row=quad*4+reg
// ---------------------------------------------------------------------------
__global__ __launch_bounds__(512, 2) void gru_kernel(
    const float* __restrict__ x,       // [T][B][D]
    const float* __restrict__ bhh_s,   // [384] scaled b_hh
    const short* __restrict__ wc_bf,   // [384][128] bf16 (scaled)
    const short* __restrict__ whh_bf,  // [384][128] bf16 (scaled)
    const float* __restrict__ bc,      // [384] (scaled)
    float* __restrict__ out)           // [B][H]
{
  const int tid = threadIdx.x;
  const int w   = tid >> 6;       // wave 0..7
  const int l   = tid & 63;
  const int q   = l >> 4;         // quad
  const int c   = l & 15;         // col-in-tile / A-row
  const int b0  = blockIdx.x * 2;

  __shared__ f32x4 gi4[2][16][128];        // [buf][m=2*step+chain][gatecol] (r,z,n,_) 64 KB
  __shared__ short hbuf[2][2][HSTRIDE];    // [parity][chain][col] bf16, 320B chain stride

  const f32x4 zero4 = {0.f, 0.f, 0.f, 0.f};

  if (w < 4) {
    // ================= CONSUMER =================
    const int half = q & 1;                    // 0 -> Tt0 cols, 1 -> Tt1 cols
    const int ch   = q >> 1;                   // this lane's chain
    const int colX = w * 32 + (half << 4) + c; // this lane's hidden col

    bf16x8 Bh[3][2][4];
    #pragma unroll
    for (int g = 0; g < 3; ++g)
      #pragma unroll
      for (int Tt = 0; Tt < 2; ++Tt)
        #pragma unroll
        for (int kt = 0; kt < 4; ++kt)
          Bh[g][Tt][kt] = *(const bf16x8*)(whh_bf +
              (g * 128 + w * 32 + Tt * 16 + c) * 128 + kt * 32 + q * 8);
    const float bhn = bhh_s[256 + colX];       // scaled by 2*log2e

    // zero parity-0 hbuf (320 shorts incl. pad) with the 256 consumer tids
    ((short*)hbuf)[tid] = 0;
    if (tid < 2 * HSTRIDE - 256) ((short*)hbuf)[256 + tid] = 0;
    float hp = 0.f;
    __syncthreads();

    // A-row c -> chain c>>3 (rows 0-7: chain0, 8-15: chain1), broadcast reads
    const short* hb0 = &hbuf[0][c >> 3][q * 8];
    const short* hb1 = &hbuf[1][c >> 3][q * 8];

    __builtin_amdgcn_s_setprio(1);
    for (int cc = 0; cc < NCHUNK; ++cc) {
      const f32x4* gp = &gi4[cc & 1][ch][colX];
      f32x4 gcur = gp[0];   // chunk top: buffer fully published before this chunk
      #pragma unroll
      for (int s = 0; s < 8; ++s) {
        const short* hb = (s & 1) ? hb1 : hb0;
        bf16x8 Ah[4];
        #pragma unroll
        for (int kt = 0; kt < 4; ++kt)
          Ah[kt] = *(const bf16x8*)(hb + kt * 32);
        f32x4 gnext = zero4;
        if (s < 7) gnext = gp[2 * (s + 1) * 128];   // same-buffer prefetch only

        // ---- 24 INDEPENDENT partial MFMAs: gate-major r -> n -> z ----
        f32x4 pr[2][4], pn[2][4], pz[2][4];
        #pragma unroll
        for (int kt = 0; kt < 4; ++kt) {
          pr[0][kt] = __builtin_amdgcn_mfma_f32_16x16x32_bf16(Ah[kt], Bh[0][0][kt], zero4, 0, 0, 0);
          pr[1][kt] = __builtin_amdgcn_mfma_f32_16x16x32_bf16(Ah[kt], Bh[0][1][kt], zero4, 0, 0, 0);
        }
        #pragma unroll
        for (int kt = 0; kt < 4; ++kt) {
          pn[0][kt] = __builtin_amdgcn_mfma_f32_16x16x32_bf16(Ah[kt], Bh[2][0][kt], zero4, 0, 0, 0);
          pn[1][kt] = __builtin_amdgcn_mfma_f32_16x16x32_bf16(Ah[kt], Bh[2][1][kt], zero4, 0, 0, 0);
        }
        #pragma unroll
        for (int kt = 0; kt < 4; ++kt) {
          pz[0][kt] = __builtin_amdgcn_mfma_f32_16x16x32_bf16(Ah[kt], Bh[1][0][kt], zero4, 0, 0, 0);
          pz[1][kt] = __builtin_amdgcn_mfma_f32_16x16x32_bf16(Ah[kt], Bh[1][1][kt], zero4, 0, 0, 0);
        }

        // ---- gate tail: partial sums + trans chain (r, n, z order) ----
        const float ghr = half ? ((pr[1][0][0] + pr[1][1][0]) + (pr[1][2][0] + pr[1][3][0]))
                               : ((pr[0][0][0] + pr[0][1][0]) + (pr[0][2][0] + pr[0][3][0]));
        const float rg = __builtin_amdgcn_rcpf(1.f + __builtin_amdgcn_exp2f(-(gcur[0] + ghr)));
        const float ghn = half ? ((pn[1][0][0] + pn[1][1][0]) + (pn[1][2][0] + pn[1][3][0]))
                               : ((pn[0][0][0] + pn[0][1][0]) + (pn[0][2][0] + pn[0][3][0]));
        // n in 2*log2e units: tanh(nv) = 1 - 2/(exp2(nv_s)+1); saturates clean.
        const float nv = fmaf(rg, ghn + bhn, gcur[2]);
        const float e  = __builtin_amdgcn_exp2f(nv);
        const float nn = 1.f - 2.f * __builtin_amdgcn_rcpf(e + 1.f);
        const float ghz = half ? ((pz[1][0][0] + pz[1][1][0]) + (pz[1][2][0] + pz[1][3][0]))
                               : ((pz[0][0][0] + pz[0][1][0]) + (pz[0][2][0] + pz[0][3][0]));
        const float zg = __builtin_amdgcn_rcpf(1.f + __builtin_amdgcn_exp2f(-(gcur[1] + ghz)));
        const float h  = fmaf(zg, hp - nn, nn);
        hp = h;
        hbuf[(s & 1) ^ 1][ch][colX] = f2bf(h);
        gcur = gnext;
        block_sync_lds();
      }
    }
    __builtin_amdgcn_s_setprio(0);
    out[(size_t)(b0 + ch) * DIM + colX] = hp;
  } else {
    // ================= PRODUCER =================
    const int w4 = w - 4;
    const int jg0 = w4 * 32 + c, jg1 = jg0 + 16;
    bf16x8 Bc[3][2][4];
    #pragma unroll
    for (int g = 0; g < 3; ++g)
      #pragma unroll
      for (int Tt = 0; Tt < 2; ++Tt)
        #pragma unroll
        for (int kt = 0; kt < 4; ++kt)
          Bc[g][Tt][kt] = *(const bf16x8*)(wc_bf +
              (g * 128 + w4 * 32 + Tt * 16 + c) * 128 + kt * 32 + q * 8);
    const float fr0 = bc[jg0]       + bhh_s[jg0];
    const float fz0 = bc[128 + jg0] + bhh_s[128 + jg0];
    const float fn0 = bc[256 + jg0];
    const float fr1 = bc[jg1]       + bhh_s[jg1];
    const float fz1 = bc[128 + jg1] + bhh_s[128 + jg1];
    const float fn1 = bc[256 + jg1];

    const int trel = c >> 1, chn = c & 1;   // A-row m = c = 2*trel + chn
    f32x4 xv[8];

    // ---- pre-phase: build chunk 0 into buf 0, then prefetch chunk 1
    {
      const float* xb = x + ((size_t)trel * BATCH + (b0 + chn)) * DIM + q * 8;
      f32x4 xt[8];
      #pragma unroll
      for (int kt = 0; kt < 4; ++kt) {
        xt[2 * kt]     = *(const f32x4*)(xb + kt * 32);
        xt[2 * kt + 1] = *(const f32x4*)(xb + kt * 32 + 4);
      }
      bf16x8 Ax[4];
      #pragma unroll
      for (int kt = 0; kt < 4; ++kt) {
        const f32x4 v0 = xt[2 * kt], v1 = xt[2 * kt + 1];
        bf16x8 a;
        a[0] = f2bf(v0[0]); a[1] = f2bf(v0[1]); a[2] = f2bf(v0[2]); a[3] = f2bf(v0[3]);
        a[4] = f2bf(v1[0]); a[5] = f2bf(v1[1]); a[6] = f2bf(v1[2]); a[7] = f2bf(v1[3]);
        Ax[kt] = a;
      }
      f32x4 ga[2][3];
      #pragma unroll
      for (int g = 0; g < 3; ++g) {
        ga[0][g] = __builtin_amdgcn_mfma_f32_16x16x32_bf16(Ax[0], Bc[g][0][0], zero4, 0, 0, 0);
        ga[1][g] = __builtin_amdgcn_mfma_f32_16x16x32_bf16(Ax[0], Bc[g][1][0], zero4, 0, 0, 0);
      }
      #pragma unroll
      for (int kt = 1; kt < 4; ++kt)
        #pragma unroll
        for (int g = 0; g < 3; ++g) {
          ga[0][g] = __builtin_amdgcn_mfma_f32_16x16x32_bf16(Ax[kt], Bc[g][0][kt], ga[0][g], 0, 0, 0);
          ga[1][g] = __builtin_amdgcn_mfma_f32_16x16x32_bf16(Ax[kt], Bc[g][1][kt], ga[1][g], 0, 0, 0);
        }
      #pragma unroll
      for (int r = 0; r < 4; ++r) {
        f32x4 vA = {ga[0][0][r] + fr0, ga[0][1][r] + fz0, ga[0][2][r] + fn0, 0.f};
        f32x4 vB = {ga[1][0][r] + fr1, ga[1][1][r] + fz1, ga[1][2][r] + fn1, 0.f};
        gi4[0][4 * q + r][jg0] = vA;
        gi4[0][4 * q + r][jg1] = vB;
      }
      const float* xb1 = x + ((size_t)(8 + trel) * BATCH + (b0 + chn)) * DIM + q * 8;
      #pragma unroll
      for (int kt = 0; kt < 4; ++kt) {
        xv[2 * kt]     = *(const f32x4*)(xb1 + kt * 32);
        xv[2 * kt + 1] = *(const f32x4*)(xb1 + kt * 32 + 4);
      }
    }
    __syncthreads();

    for (int cc = 0; cc < NCHUNK; ++cc) {
      const int tc = cc + 1;            // chunk being produced
      bf16x8 Ax[4];
      f32x4 ga[2][3];
      #pragma unroll
      for (int s = 0; s < 8; ++s) {
        if (tc < NCHUNK) {
          // LEVELED f2bf: convert Ax[kt] one per step, just-in-time.
          // kt first used at s: kt0->1, kt1->2, kt2->4, kt3->5.
          if (s == 0 || s == 1 || s == 3 || s == 4) {
            const int ck = (s < 2) ? s : s - 1;       // 0,1,2,3
            const f32x4 v0 = xv[2 * ck], v1 = xv[2 * ck + 1];
            bf16x8 a;
            a[0] = f2bf(v0[0]); a[1] = f2bf(v0[1]); a[2] = f2bf(v0[2]); a[3] = f2bf(v0[3]);
            a[4] = f2bf(v1[0]); a[5] = f2bf(v1[1]); a[6] = f2bf(v1[2]); a[7] = f2bf(v1[3]);
            Ax[ck] = a;
          }
          if (s >= 1 && s <= 6) {
            // LEVELED MFMA schedule: 2 (g,kt)-units = 4 MFMAs per step, s=1..6.
            // Unit u = 2*(s-1)+uu -> kt = u/3, g = u%3; kt==0 consumes zero C.
            #pragma unroll
            for (int uu = 0; uu < 2; ++uu) {
              const int u = 2 * (s - 1) + uu;
              const int kt = u / 3, g = u % 3;
              if (kt == 0) {
                ga[0][g] = __builtin_amdgcn_mfma_f32_16x16x32_bf16(Ax[0], Bc[g][0][0], zero4, 0, 0, 0);
                ga[1][g] = __builtin_amdgcn_mfma_f32_16x16x32_bf16(Ax[0], Bc[g][1][0], zero4, 0, 0, 0);
              } else {
                ga[0][g] = __builtin_amdgcn_mfma_f32_16x16x32_bf16(Ax[kt], Bc[g][0][kt], ga[0][g], 0, 0, 0);
                ga[1][g] = __builtin_amdgcn_mfma_f32_16x16x32_bf16(Ax[kt], Bc[g][1][kt], ga[1][g], 0, 0, 0);
              }
            }
            if (s == 5 && tc + 1 < NCHUNK) {  // prefetch x for chunk tc+1 (stays in flight)
              const float* xb = x + ((size_t)((tc + 1) * 8 + trel) * BATCH + (b0 + chn)) * DIM + q * 8;
              #pragma unroll
              for (int kt = 0; kt < 4; ++kt) {
                xv[2 * kt]     = *(const f32x4*)(xb + kt * 32);
                xv[2 * kt + 1] = *(const f32x4*)(xb + kt * 32 + 4);
              }
            }
          } else if (s == 7) {  // bias fold + publish gi for chunk tc
            const int nbuf = tc & 1;
            #pragma unroll
            for (int r = 0; r < 4; ++r) {
              f32x4 vA = {ga[0][0][r] + fr0, ga[0][1][r] + fz0, ga[0][2][r] + fn0, 0.f};
              f32x4 vB = {ga[1][0][r] + fr1, ga[1][1][r] + fz1, ga[1][2][r] + fn1, 0.f};
              gi4[nbuf][4 * q + r][jg0] = vA;
              gi4[nbuf][4 * q + r][jg1] = vB;
            }
          }
        }
        block_sync_lds();
      }
    }
  }
}

// ---------------------------------------------------------------------------
extern "C" void kernel_launch(void* const* d_in, const int* in_sizes, int n_in,
                              void* d_out, int out_size, void* d_ws, size_t ws_size,
                              hipStream_t stream) {
  const float* x    = (const float*)d_in[0];
  const float* W1   = (const float*)d_in[1];
  const float* b1   = (const float*)d_in[2];
  const float* W_ih = (const float*)d_in[3];
  const float* W_hh = (const float*)d_in[4];
  const float* b_ih = (const float*)d_in[5];
  const float* b_hh = (const float*)d_in[6];
  float* out = (float*)d_out;

  char* ws = (char*)d_ws;
  short* wc_bf  = (short*)(ws);             // 384*128 bf16
  short* whh_bf = (short*)(ws + 98304);     // 384*128 bf16
  float* bc     = (float*)(ws + 196608);    // 384 fp32
  float* bhh_s  = (float*)(ws + 198144);    // 384 fp32 (scaled b_hh)

  prep_kernel<<<dim3(G3), dim3(128), 0, stream>>>(W1, b1, W_ih, W_hh, b_ih, b_hh,
                                                  wc_bf, whh_bf, bc, bhh_s);
  gru_kernel<<<dim3(BATCH / 2), dim3(512), 0, stream>>>(x, bhh_s, wc_bf, whh_bf, bc, out);
}

// Round 8
// 670.206 us; speedup vs baseline: 1.0607x; 1.0607x over previous
//
#include <hip/hip_runtime.h>
#include <hip/hip_bf16.h>

// Problem constants (reference: T,B,D,H = 1024,512,128,128)
#define T_STEPS 1024
#define BATCH   512
#define DIM     128
#define G3      384          // 3*H gate rows
#define NCHUNK  (T_STEPS/8)  // 128 chunks of 8 steps

typedef __attribute__((ext_vector_type(8))) short bf16x8;
typedef __attribute__((ext_vector_type(4))) float f32x4;

#define LOG2E  1.44269504f   // r,z gate rows pre-scaled by -log2(e)  (negated: sigmoid needs exp(-x))
#define LOG2E2 2.88539008f   // n gate rows pre-scaled by +2*log2(e)

// hbuf row stride in shorts: 128 cols + 32 pad -> chain stride 320B.
// Proven round 4: SQ_LDS_BANK_CONFLICT 16.8M -> 0.
#define HSTRIDE 160

__device__ __forceinline__ short f2bf(float f) {
  unsigned u = __builtin_bit_cast(unsigned, f);
  u += 0x7FFFu + ((u >> 16) & 1u);   // round-to-nearest-even
  return (short)(u >> 16);
}

// LDS-only barrier: drains LDS ops for cross-wave visibility but does NOT
// drain vmcnt -> producer global prefetch stays in flight across steps.
__device__ __forceinline__ void block_sync_lds() {
  asm volatile("s_waitcnt lgkmcnt(0)\n\ts_barrier" ::: "memory");
}

// ---------------------------------------------------------------------------
// Prep: Wc = W_ih @ W1 (bf16), W_hh -> bf16, bc = W_ih @ b1 + b_ih (fp32).
// r,z rows scaled by -log2e (sigmoid negate folded into the weights);
// n rows scaled by +2*log2e (tanh-via-exp2). Gate math is then bare exp2.
// ---------------------------------------------------------------------------
__global__ void prep_kernel(const float* __restrict__ W1, const float* __restrict__ b1,
                            const float* __restrict__ W_ih, const float* __restrict__ W_hh,
                            const float* __restrict__ b_ih, const float* __restrict__ b_hh,
                            short* __restrict__ wc_bf, short* __restrict__ whh_bf,
                            float* __restrict__ bc, float* __restrict__ bhh_s) {
  const int g = blockIdx.x;
  const int d = threadIdx.x;
  const float sg = (g < 256) ? -LOG2E : LOG2E2;   // NEGATED for r,z rows
  float acc = 0.f;
  #pragma unroll 4
  for (int k = 0; k < 128; ++k)
    acc = fmaf(W_ih[g * 128 + k], W1[k * 128 + d], acc);
  wc_bf[g * 128 + d]  = f2bf(acc * sg);
  whh_bf[g * 128 + d] = f2bf(W_hh[g * 128 + d] * sg);

  __shared__ float red[128];
  red[d] = W_ih[g * 128 + d] * b1[d];
  __syncthreads();
  #pragma unroll
  for (int s = 64; s > 0; s >>= 1) {
    if (d < s) red[d] += red[d + s];
    __syncthreads();
  }
  if (d == 0) {
    bc[g]    = (red[0] + b_ih[g]) * sg;
    bhh_s[g] = b_hh[g] * sg;
  }
}

// ---------------------------------------------------------------------------
// Main GRU kernel. 256 blocks (2 chains) x 512 threads (8 waves, 2/SIMD).
// Waves 0-3 = CONSUMERS (24 MFMA/step each, R5 depth-2 split-K — R7 proved
// C-chained MFMAs don't stall, so depth-2 is optimal); waves 4-7 = PRODUCERS
// (gi for chunk c+1, leveled 4 MFMA/step + 8 f2bf/step).
//
// C-OPERAND BIAS INJECTION (this round): the gate tail only reads reg0 of
// each accumulator (rows 4q are the duplicate-canonical rows; rows 4q+1..3
// are read by NO lane). So the A-chain head MFMAs are seeded with:
//   rA: C = gcur      (reg0 = gcur[0] -> gi_r pre-added in the matrix pipe)
//   zA: C = {gcur[1]} (gi_z)          nA: C = {bhn} (n-gate hh-bias)
// This moves 4 serial VALU adds per step into the MFMAs for free. With the
// r,z sign pre-fold (prep), the sigmoid is rcp(1+exp2(arg)) with no negate.
// mfma_f32_16x16x32_bf16 layouts (m89-verified):
//   A[m=lane&15][k=quad*8+j], B[k=quad*8+j][n=lane&15], D: col=lane&15,row=quad*4+reg
// ---------------------------------------------------------------------------
__global__ __launch_bounds__(512, 2) void gru_kernel(
    const float* __restrict__ x,       // [T][B][D]
    const float* __restrict__ bhh_s,   // [384] scaled b_hh
    const short* __restrict__ wc_bf,   // [384][128] bf16 (scaled)
    const short* __restrict__ whh_bf,  // [384][128] bf16 (scaled)
    const float* __restrict__ bc,      // [384] (scaled)
    float* __restrict__ out)           // [B][H]
{
  const int tid = threadIdx.x;
  const int w   = tid >> 6;       // wave 0..7
  const int l   = tid & 63;
  const int q   = l >> 4;         // quad
  const int c   = l & 15;         // col-in-tile / A-row
  const int b0  = blockIdx.x * 2;

  __shared__ f32x4 gi4[2][16][128];        // [buf][m=2*step+chain][gatecol] (r,z,n,_) 64 KB
  __shared__ short hbuf[2][2][HSTRIDE];    // [parity][chain][col] bf16, 320B chain stride

  const f32x4 zero4 = {0.f, 0.f, 0.f, 0.f};

  if (w < 4) {
    // ================= CONSUMER =================
    const int half = q & 1;                    // 0 -> Tt0 cols, 1 -> Tt1 cols
    const int ch   = q >> 1;                   // this lane's chain
    const int colX = w * 32 + (half << 4) + c; // this lane's hidden col

    bf16x8 Bh[3][2][4];
    #pragma unroll
    for (int g = 0; g < 3; ++g)
      #pragma unroll
      for (int Tt = 0; Tt < 2; ++Tt)
        #pragma unroll
        for (int kt = 0; kt < 4; ++kt)
          Bh[g][Tt][kt] = *(const bf16x8*)(whh_bf +
              (g * 128 + w * 32 + Tt * 16 + c) * 128 + kt * 32 + q * 8);
    const float bhn = bhh_s[256 + colX];       // scaled by 2*log2e
    const f32x4 bhn4 = {bhn, 0.f, 0.f, 0.f};   // C-seed for nA (reg0 = bhn)

    // zero parity-0 hbuf (320 shorts incl. pad) with the 256 consumer tids
    ((short*)hbuf)[tid] = 0;
    if (tid < 2 * HSTRIDE - 256) ((short*)hbuf)[256 + tid] = 0;
    float hp = 0.f;
    __syncthreads();

    // A-row c -> chain c>>3 (rows 0-7: chain0, 8-15: chain1), broadcast reads
    const short* hb0 = &hbuf[0][c >> 3][q * 8];
    const short* hb1 = &hbuf[1][c >> 3][q * 8];

    __builtin_amdgcn_s_setprio(1);
    for (int cc = 0; cc < NCHUNK; ++cc) {
      const f32x4* gp = &gi4[cc & 1][ch][colX];
      f32x4 gcur = gp[0];   // chunk top: buffer fully published before this chunk
      #pragma unroll
      for (int s = 0; s < 8; ++s) {
        const short* hb = (s & 1) ? hb1 : hb0;
        bf16x8 Ah[4];
        #pragma unroll
        for (int kt = 0; kt < 4; ++kt)
          Ah[kt] = *(const bf16x8*)(hb + kt * 32);
        // unconditional same-buffer prefetch ((s+1)&7 -> gp[0] at s==7, dead value)
        f32x4 gnext = gp[2 * ((s + 1) & 7) * 128];
        const f32x4 gz = {gcur[1], 0.f, 0.f, 0.f};   // C-seed for zA

        // ---- phase 1: 12 chain heads; A-heads carry the gate bias in C ----
        f32x4 r0A = __builtin_amdgcn_mfma_f32_16x16x32_bf16(Ah[0], Bh[0][0][0], gcur, 0, 0, 0);
        f32x4 r1A = __builtin_amdgcn_mfma_f32_16x16x32_bf16(Ah[0], Bh[0][1][0], gcur, 0, 0, 0);
        f32x4 r0B = __builtin_amdgcn_mfma_f32_16x16x32_bf16(Ah[2], Bh[0][0][2], zero4, 0, 0, 0);
        f32x4 r1B = __builtin_amdgcn_mfma_f32_16x16x32_bf16(Ah[2], Bh[0][1][2], zero4, 0, 0, 0);
        f32x4 n0A = __builtin_amdgcn_mfma_f32_16x16x32_bf16(Ah[0], Bh[2][0][0], bhn4, 0, 0, 0);
        f32x4 n1A = __builtin_amdgcn_mfma_f32_16x16x32_bf16(Ah[0], Bh[2][1][0], bhn4, 0, 0, 0);
        f32x4 n0B = __builtin_amdgcn_mfma_f32_16x16x32_bf16(Ah[2], Bh[2][0][2], zero4, 0, 0, 0);
        f32x4 n1B = __builtin_amdgcn_mfma_f32_16x16x32_bf16(Ah[2], Bh[2][1][2], zero4, 0, 0, 0);
        f32x4 z0A = __builtin_amdgcn_mfma_f32_16x16x32_bf16(Ah[0], Bh[1][0][0], gz, 0, 0, 0);
        f32x4 z1A = __builtin_amdgcn_mfma_f32_16x16x32_bf16(Ah[0], Bh[1][1][0], gz, 0, 0, 0);
        f32x4 z0B = __builtin_amdgcn_mfma_f32_16x16x32_bf16(Ah[2], Bh[1][0][2], zero4, 0, 0, 0);
        f32x4 z1B = __builtin_amdgcn_mfma_f32_16x16x32_bf16(Ah[2], Bh[1][1][2], zero4, 0, 0, 0);

        // ---- phase 2: 12 DEPENDENTS, ordered r -> n -> z ----
        r0A = __builtin_amdgcn_mfma_f32_16x16x32_bf16(Ah[1], Bh[0][0][1], r0A, 0, 0, 0);
        r1A = __builtin_amdgcn_mfma_f32_16x16x32_bf16(Ah[1], Bh[0][1][1], r1A, 0, 0, 0);
        r0B = __builtin_amdgcn_mfma_f32_16x16x32_bf16(Ah[3], Bh[0][0][3], r0B, 0, 0, 0);
        r1B = __builtin_amdgcn_mfma_f32_16x16x32_bf16(Ah[3], Bh[0][1][3], r1B, 0, 0, 0);
        n0A = __builtin_amdgcn_mfma_f32_16x16x32_bf16(Ah[1], Bh[2][0][1], n0A, 0, 0, 0);
        n1A = __builtin_amdgcn_mfma_f32_16x16x32_bf16(Ah[1], Bh[2][1][1], n1A, 0, 0, 0);
        n0B = __builtin_amdgcn_mfma_f32_16x16x32_bf16(Ah[3], Bh[2][0][3], n0B, 0, 0, 0);
        n1B = __builtin_amdgcn_mfma_f32_16x16x32_bf16(Ah[3], Bh[2][1][3], n1B, 0, 0, 0);
        z0A = __builtin_amdgcn_mfma_f32_16x16x32_bf16(Ah[1], Bh[1][0][1], z0A, 0, 0, 0);
        z1A = __builtin_amdgcn_mfma_f32_16x16x32_bf16(Ah[1], Bh[1][1][1], z1A, 0, 0, 0);
        z0B = __builtin_amdgcn_mfma_f32_16x16x32_bf16(Ah[3], Bh[1][0][3], z0B, 0, 0, 0);
        z1B = __builtin_amdgcn_mfma_f32_16x16x32_bf16(Ah[3], Bh[1][1][3], z1B, 0, 0, 0);

        // ---- gate tail: biases already in reg0; sigmoid negate pre-folded ----
        const float arg_r = half ? (r1A[0] + r1B[0]) : (r0A[0] + r0B[0]);
        const float rg = __builtin_amdgcn_rcpf(1.f + __builtin_amdgcn_exp2f(arg_r));
        const float ghn_b = half ? (n1A[0] + n1B[0]) : (n0A[0] + n0B[0]);
        // n in 2*log2e units: tanh(nv) = 1 - 2/(exp2(nv_s)+1); saturates clean.
        const float nv = fmaf(rg, ghn_b, gcur[2]);
        const float e  = __builtin_amdgcn_exp2f(nv);
        const float nn = 1.f - 2.f * __builtin_amdgcn_rcpf(e + 1.f);
        const float arg_z = half ? (z1A[0] + z1B[0]) : (z0A[0] + z0B[0]);
        const float zg = __builtin_amdgcn_rcpf(1.f + __builtin_amdgcn_exp2f(arg_z));
        const float h  = fmaf(zg, hp - nn, nn);
        hp = h;
        hbuf[(s & 1) ^ 1][ch][colX] = f2bf(h);
        gcur = gnext;
        block_sync_lds();
      }
    }
    __builtin_amdgcn_s_setprio(0);
    out[(size_t)(b0 + ch) * DIM + colX] = hp;
  } else {
    // ================= PRODUCER =================
    const int w4 = w - 4;
    const int jg0 = w4 * 32 + c, jg1 = jg0 + 16;
    bf16x8 Bc[3][2][4];
    #pragma unroll
    for (int g = 0; g < 3; ++g)
      #pragma unroll
      for (int Tt = 0; Tt < 2; ++Tt)
        #pragma unroll
        for (int kt = 0; kt < 4; ++kt)
          Bc[g][Tt][kt] = *(const bf16x8*)(wc_bf +
              (g * 128 + w4 * 32 + Tt * 16 + c) * 128 + kt * 32 + q * 8);
    const float fr0 = bc[jg0]       + bhh_s[jg0];
    const float fz0 = bc[128 + jg0] + bhh_s[128 + jg0];
    const float fn0 = bc[256 + jg0];
    const float fr1 = bc[jg1]       + bhh_s[jg1];
    const float fz1 = bc[128 + jg1] + bhh_s[128 + jg1];
    const float fn1 = bc[256 + jg1];

    const int trel = c >> 1, chn = c & 1;   // A-row m = c = 2*trel + chn
    f32x4 xv[8];

    // ---- pre-phase: build chunk 0 into buf 0, then prefetch chunk 1
    {
      const float* xb = x + ((size_t)trel * BATCH + (b0 + chn)) * DIM + q * 8;
      f32x4 xt[8];
      #pragma unroll
      for (int kt = 0; kt < 4; ++kt) {
        xt[2 * kt]     = *(const f32x4*)(xb + kt * 32);
        xt[2 * kt + 1] = *(const f32x4*)(xb + kt * 32 + 4);
      }
      bf16x8 Ax[4];
      #pragma unroll
      for (int kt = 0; kt < 4; ++kt) {
        const f32x4 v0 = xt[2 * kt], v1 = xt[2 * kt + 1];
        bf16x8 a;
        a[0] = f2bf(v0[0]); a[1] = f2bf(v0[1]); a[2] = f2bf(v0[2]); a[3] = f2bf(v0[3]);
        a[4] = f2bf(v1[0]); a[5] = f2bf(v1[1]); a[6] = f2bf(v1[2]); a[7] = f2bf(v1[3]);
        Ax[kt] = a;
      }
      f32x4 ga[2][3];
      #pragma unroll
      for (int g = 0; g < 3; ++g) {
        ga[0][g] = __builtin_amdgcn_mfma_f32_16x16x32_bf16(Ax[0], Bc[g][0][0], zero4, 0, 0, 0);
        ga[1][g] = __builtin_amdgcn_mfma_f32_16x16x32_bf16(Ax[0], Bc[g][1][0], zero4, 0, 0, 0);
      }
      #pragma unroll
      for (int kt = 1; kt < 4; ++kt)
        #pragma unroll
        for (int g = 0; g < 3; ++g) {
          ga[0][g] = __builtin_amdgcn_mfma_f32_16x16x32_bf16(Ax[kt], Bc[g][0][kt], ga[0][g], 0, 0, 0);
          ga[1][g] = __builtin_amdgcn_mfma_f32_16x16x32_bf16(Ax[kt], Bc[g][1][kt], ga[1][g], 0, 0, 0);
        }
      #pragma unroll
      for (int r = 0; r < 4; ++r) {
        f32x4 vA = {ga[0][0][r] + fr0, ga[0][1][r] + fz0, ga[0][2][r] + fn0, 0.f};
        f32x4 vB = {ga[1][0][r] + fr1, ga[1][1][r] + fz1, ga[1][2][r] + fn1, 0.f};
        gi4[0][4 * q + r][jg0] = vA;
        gi4[0][4 * q + r][jg1] = vB;
      }
      const float* xb1 = x + ((size_t)(8 + trel) * BATCH + (b0 + chn)) * DIM + q * 8;
      #pragma unroll
      for (int kt = 0; kt < 4; ++kt) {
        xv[2 * kt]     = *(const f32x4*)(xb1 + kt * 32);
        xv[2 * kt + 1] = *(const f32x4*)(xb1 + kt * 32 + 4);
      }
    }
    __syncthreads();

    for (int cc = 0; cc < NCHUNK; ++cc) {
      const int tc = cc + 1;            // chunk being produced
      bf16x8 Ax[4];
      f32x4 ga[2][3];
      #pragma unroll
      for (int s = 0; s < 8; ++s) {
        if (tc < NCHUNK) {
          // LEVELED f2bf: convert Ax[kt] one per step, just-in-time.
          // kt first used at s: kt0->1, kt1->2, kt2->4, kt3->5.
          if (s == 0 || s == 1 || s == 3 || s == 4) {
            const int ck = (s < 2) ? s : s - 1;       // 0,1,2,3
            const f32x4 v0 = xv[2 * ck], v1 = xv[2 * ck + 1];
            bf16x8 a;
            a[0] = f2bf(v0[0]); a[1] = f2bf(v0[1]); a[2] = f2bf(v0[2]); a[3] = f2bf(v0[3]);
            a[4] = f2bf(v1[0]); a[5] = f2bf(v1[1]); a[6] = f2bf(v1[2]); a[7] = f2bf(v1[3]);
            Ax[ck] = a;
          }
          if (s >= 1 && s <= 6) {
            // LEVELED MFMA schedule: 2 (g,kt)-units = 4 MFMAs per step, s=1..6.
            // Unit u = 2*(s-1)+uu -> kt = u/3, g = u%3; kt==0 consumes zero C.
            #pragma unroll
            for (int uu = 0; uu < 2; ++uu) {
              const int u = 2 * (s - 1) + uu;
              const int kt = u / 3, g = u % 3;
              if (kt == 0) {
                ga[0][g] = __builtin_amdgcn_mfma_f32_16x16x32_bf16(Ax[0], Bc[g][0][0], zero4, 0, 0, 0);
                ga[1][g] = __builtin_amdgcn_mfma_f32_16x16x32_bf16(Ax[0], Bc[g][1][0], zero4, 0, 0, 0);
              } else {
                ga[0][g] = __builtin_amdgcn_mfma_f32_16x16x32_bf16(Ax[kt], Bc[g][0][kt], ga[0][g], 0, 0, 0);
                ga[1][g] = __builtin_amdgcn_mfma_f32_16x16x32_bf16(Ax[kt], Bc[g][1][kt], ga[1][g], 0, 0, 0);
              }
            }
            if (s == 5 && tc + 1 < NCHUNK) {  // prefetch x for chunk tc+1 (stays in flight)
              const float* xb = x + ((size_t)((tc + 1) * 8 + trel) * BATCH + (b0 + chn)) * DIM + q * 8;
              #pragma unroll
              for (int kt = 0; kt < 4; ++kt) {
                xv[2 * kt]     = *(const f32x4*)(xb + kt * 32);
                xv[2 * kt + 1] = *(const f32x4*)(xb + kt * 32 + 4);
              }
            }
          } else if (s == 7) {  // bias fold + publish gi for chunk tc
            const int nbuf = tc & 1;
            #pragma unroll
            for (int r = 0; r < 4; ++r) {
              f32x4 vA = {ga[0][0][r] + fr0, ga[0][1][r] + fz0, ga[0][2][r] + fn0, 0.f};
              f32x4 vB = {ga[1][0][r] + fr1, ga[1][1][r] + fz1, ga[1][2][r] + fn1, 0.f};
              gi4[nbuf][4 * q + r][jg0] = vA;
              gi4[nbuf][4 * q + r][jg1] = vB;
            }
          }
        }
        block_sync_lds();
      }
    }
  }
}

// ---------------------------------------------------------------------------
extern "C" void kernel_launch(void* const* d_in, const int* in_sizes, int n_in,
                              void* d_out, int out_size, void* d_ws, size_t ws_size,
                              hipStream_t stream) {
  const float* x    = (const float*)d_in[0];
  const float* W1   = (const float*)d_in[1];
  const float* b1   = (const float*)d_in[2];
  const float* W_ih = (const float*)d_in[3];
  const float* W_hh = (const float*)d_in[4];
  const float* b_ih = (const float*)d_in[5];
  const float* b_hh = (const float*)d_in[6];
  float* out = (float*)d_out;

  char* ws = (char*)d_ws;
  short* wc_bf  = (short*)(ws);             // 384*128 bf16
  short* whh_bf = (short*)(ws + 98304);     // 384*128 bf16
  float* bc     = (float*)(ws + 196608);    // 384 fp32
  float* bhh_s  = (float*)(ws + 198144);    // 384 fp32 (scaled b_hh)

  prep_kernel<<<dim3(G3), dim3(128), 0, stream>>>(W1, b1, W_ih, W_hh, b_ih, b_hh,
                                                  wc_bf, whh_bf, bc, bhh_s);
  gru_kernel<<<dim3(BATCH / 2), dim3(512), 0, stream>>>(x, bhh_s, wc_bf, whh_bf, bc, out);
}

// Round 9
// 615.573 us; speedup vs baseline: 1.1548x; 1.0888x over previous
//
#include <hip/hip_runtime.h>
#include <hip/hip_bf16.h>

// Problem constants (reference: T,B,D,H = 1024,512,128,128)
#define T_STEPS 1024
#define BATCH   512
#define DIM     128
#define G3      384          // 3*H gate rows
#define NCHUNK  (T_STEPS/8)  // 128 chunks of 8 steps

typedef __attribute__((ext_vector_type(8))) short bf16x8;
typedef __attribute__((ext_vector_type(4))) float f32x4;
typedef __attribute__((ext_vector_type(4))) int   i32x4;

#define LOG2E  1.44269504f   // r,z rows scaled by -log2(e) (sigmoid negate folded)
#define LOG2E2 2.88539008f   // n rows scaled by +2*log2(e) (tanh-via-exp2)

__device__ __forceinline__ short f2bf(float f) {
  unsigned u = __builtin_bit_cast(unsigned, f);
  u += 0x7FFFu + ((u >> 16) & 1u);   // round-to-nearest-even
  return (short)(u >> 16);
}

// LDS-only barrier: drains LDS ops for cross-wave visibility but does NOT
// drain vmcnt -> producer global prefetch stays in flight across steps.
__device__ __forceinline__ void block_sync_lds() {
  asm volatile("s_waitcnt lgkmcnt(0)\n\ts_barrier" ::: "memory");
}

// ---------------------------------------------------------------------------
// Prep: Wc = W_ih @ W1 (bf16, gate-scaled), bc = (W_ih@b1 + b_ih)*sg,
// bhh_s = b_hh*sg, and W_hh -> INT8 with per-row scale:
//   whh_i8[g][k] = rint(W_hh[g][k] * 127 / rowmax_g)
//   dqs[g]       = sg * rowmax_g / 127^2     (i32 acc -> scaled-float dequant)
// ---------------------------------------------------------------------------
__global__ void prep_kernel(const float* __restrict__ W1, const float* __restrict__ b1,
                            const float* __restrict__ W_ih, const float* __restrict__ W_hh,
                            const float* __restrict__ b_ih, const float* __restrict__ b_hh,
                            short* __restrict__ wc_bf, char* __restrict__ whh_i8,
                            float* __restrict__ bc, float* __restrict__ bhh_s,
                            float* __restrict__ dqs) {
  const int g = blockIdx.x;
  const int d = threadIdx.x;
  const float sg = (g < 256) ? -LOG2E : LOG2E2;   // NEGATED for r,z rows
  float acc = 0.f;
  #pragma unroll 4
  for (int k = 0; k < 128; ++k)
    acc = fmaf(W_ih[g * 128 + k], W1[k * 128 + d], acc);
  wc_bf[g * 128 + d] = f2bf(acc * sg);

  __shared__ float red[128];
  __shared__ float srow_sh;

  // ---- per-row max of |W_hh| -> int8 quantization scale
  red[d] = fabsf(W_hh[g * 128 + d]);
  __syncthreads();
  #pragma unroll
  for (int s = 64; s > 0; s >>= 1) {
    if (d < s) red[d] = fmaxf(red[d], red[d + s]);
    __syncthreads();
  }
  if (d == 0) srow_sh = fmaxf(red[0], 1e-30f);
  __syncthreads();
  const float qs = 127.f / srow_sh;
  whh_i8[g * 128 + d] = (char)(int)rintf(W_hh[g * 128 + d] * qs);
  __syncthreads();

  // ---- bias reduction
  red[d] = W_ih[g * 128 + d] * b1[d];
  __syncthreads();
  #pragma unroll
  for (int s = 64; s > 0; s >>= 1) {
    if (d < s) red[d] += red[d + s];
    __syncthreads();
  }
  if (d == 0) {
    bc[g]    = (red[0] + b_ih[g]) * sg;
    bhh_s[g] = b_hh[g] * sg;
    dqs[g]   = sg * srow_sh / 16129.f;   // sg * rowmax / 127^2
  }
}

// ---------------------------------------------------------------------------
// Main GRU kernel. 256 blocks (2 chains) x 512 threads (8 waves, 2/SIMD).
// Waves 0-3 = CONSUMERS; waves 4-7 = PRODUCERS (gi via bf16 MFMA, unchanged).
//
// INT8 hh MATVEC (this round): h is quantized to i8 (scale 127, |h|<1 by GRU
// convexity) and W_hh to per-row-scaled i8. mfma_i32_16x16x64_i8 has 2x K and
// 2x rate vs bf16 -> consumer = 12 MFMAs/step (3 gates x 2 Ntiles x 2 kt) =
// ~245 cyc/SIMD issue vs 466. i32 accumulation is EXACT; only input
// quantization contributes error. Dequant: arg = fma((float)acc, dq_row, gi).
// Layout safety: C/D mapping is shape-determined & dtype-independent
// (m121-128 HW-verified); A/B per-quad k-window ordering cancels because both
// fragments are packed linear-k by the same lane.
// hbuf8: [parity][chain][192B]: chain offset 192 = 64 mod 128 -> the 8
// broadcast fragments (2ch x 4q x 16B) tile all 32 banks exactly; 0 conflicts.
// gi PROTOCOL (race lesson R6): only read the CURRENT chunk's gi buffer
// inside a step; (s+1)&7 wrap reads gp[0] (dead value, same buffer).
// ---------------------------------------------------------------------------
__global__ __launch_bounds__(512, 2) void gru_kernel(
    const float* __restrict__ x,       // [T][B][D]
    const float* __restrict__ bhh_s,   // [384] scaled b_hh
    const short* __restrict__ wc_bf,   // [384][128] bf16 (scaled)
    const char*  __restrict__ whh_i8,  // [384][128] int8 (per-row scaled)
    const float* __restrict__ bc,      // [384] (scaled)
    const float* __restrict__ dqs,     // [384] dequant = sg*rowmax/127^2
    float* __restrict__ out)           // [B][H]
{
  const int tid = threadIdx.x;
  const int w   = tid >> 6;       // wave 0..7
  const int l   = tid & 63;
  const int q   = l >> 4;         // quad
  const int c   = l & 15;         // col-in-tile / A-row
  const int b0  = blockIdx.x * 2;

  __shared__ f32x4 gi4[2][16][128];                  // 64 KB gi double buffer
  __shared__ __align__(16) char hbuf8[2][2][192];    // [parity][chain][col] i8

  const f32x4 zero4 = {0.f, 0.f, 0.f, 0.f};

  if (w < 4) {
    // ================= CONSUMER =================
    const int half = q & 1;                    // 0 -> Tt0 cols, 1 -> Tt1 cols
    const int ch   = q >> 1;                   // this lane's chain
    const int colX = w * 32 + (half << 4) + c; // this lane's hidden col

    // int8 B fragments: [gate][Tt][kt], 4 VGPRs each (16 bytes, k=kt*64+q*16+j)
    i32x4 Bi[3][2][2];
    #pragma unroll
    for (int g = 0; g < 3; ++g)
      #pragma unroll
      for (int Tt = 0; Tt < 2; ++Tt)
        #pragma unroll
        for (int kt = 0; kt < 2; ++kt)
          Bi[g][Tt][kt] = *(const i32x4*)(whh_i8 +
              (g * 128 + w * 32 + Tt * 16 + c) * 128 + kt * 64 + q * 16);
    const float dq_r = dqs[colX];
    const float dq_z = dqs[128 + colX];
    const float dq_n = dqs[256 + colX];
    const float bhn  = bhh_s[256 + colX];      // scaled by 2*log2e

    // zero both parities of hbuf8 (768 B) with consumer tids
    if (tid < 192) ((int*)hbuf8)[tid] = 0;
    float hp = 0.f;
    __syncthreads();

    // A-row c -> chain c>>3 (rows 0-7: chain0, 8-15: chain1), broadcast reads
    const char* hb0 = &hbuf8[0][c >> 3][q * 16];
    const char* hb1 = &hbuf8[1][c >> 3][q * 16];

    const i32x4 zeroI = {0, 0, 0, 0};

    __builtin_amdgcn_s_setprio(1);
    for (int cc = 0; cc < NCHUNK; ++cc) {
      const f32x4* gp = &gi4[cc & 1][ch][colX];
      f32x4 gcur = gp[0];   // chunk top: buffer fully published before this chunk
      #pragma unroll
      for (int s = 0; s < 8; ++s) {
        const char* hb = (s & 1) ? hb1 : hb0;
        i32x4 a0 = *(const i32x4*)(hb);         // k = q*16 + 0..15
        i32x4 a1 = *(const i32x4*)(hb + 64);    // k = 64 + q*16 + 0..15
        // unconditional same-buffer prefetch ((s+1)&7 -> gp[0] at s==7, dead)
        f32x4 gnext = gp[2 * ((s + 1) & 7) * 128];

        // ---- 6 chain heads (kt=0), order r -> n -> z ----
        i32x4 r0 = __builtin_amdgcn_mfma_i32_16x16x64_i8(a0, Bi[0][0][0], zeroI, 0, 0, 0);
        i32x4 r1 = __builtin_amdgcn_mfma_i32_16x16x64_i8(a0, Bi[0][1][0], zeroI, 0, 0, 0);
        i32x4 n0 = __builtin_amdgcn_mfma_i32_16x16x64_i8(a0, Bi[2][0][0], zeroI, 0, 0, 0);
        i32x4 n1 = __builtin_amdgcn_mfma_i32_16x16x64_i8(a0, Bi[2][1][0], zeroI, 0, 0, 0);
        i32x4 z0 = __builtin_amdgcn_mfma_i32_16x16x64_i8(a0, Bi[1][0][0], zeroI, 0, 0, 0);
        i32x4 z1 = __builtin_amdgcn_mfma_i32_16x16x64_i8(a0, Bi[1][1][0], zeroI, 0, 0, 0);
        // ---- 6 dependents (kt=1), same order (C-chaining is free, R7) ----
        r0 = __builtin_amdgcn_mfma_i32_16x16x64_i8(a1, Bi[0][0][1], r0, 0, 0, 0);
        r1 = __builtin_amdgcn_mfma_i32_16x16x64_i8(a1, Bi[0][1][1], r1, 0, 0, 0);
        n0 = __builtin_amdgcn_mfma_i32_16x16x64_i8(a1, Bi[2][0][1], n0, 0, 0, 0);
        n1 = __builtin_amdgcn_mfma_i32_16x16x64_i8(a1, Bi[2][1][1], n1, 0, 0, 0);
        z0 = __builtin_amdgcn_mfma_i32_16x16x64_i8(a1, Bi[1][0][1], z0, 0, 0, 0);
        z1 = __builtin_amdgcn_mfma_i32_16x16x64_i8(a1, Bi[1][1][1], z1, 0, 0, 0);

        // ---- gate tail: dequant fma + exp2 chain (r, n, z order) ----
        const float fr = (float)(half ? r1[0] : r0[0]);
        const float arg_r = fmaf(fr, dq_r, gcur[0]);
        const float rg = __builtin_amdgcn_rcpf(1.f + __builtin_amdgcn_exp2f(arg_r));
        const float fn = (float)(half ? n1[0] : n0[0]);
        const float tn = fmaf(fn, dq_n, bhn);
        // n in 2*log2e units: tanh(nv) = 1 - 2/(exp2(nv_s)+1); saturates clean.
        const float nv = fmaf(rg, tn, gcur[2]);
        const float e  = __builtin_amdgcn_exp2f(nv);
        const float nn = 1.f - 2.f * __builtin_amdgcn_rcpf(e + 1.f);
        const float fz = (float)(half ? z1[0] : z0[0]);
        const float arg_z = fmaf(fz, dq_z, gcur[1]);
        const float zg = __builtin_amdgcn_rcpf(1.f + __builtin_amdgcn_exp2f(arg_z));
        const float h  = fmaf(zg, hp - nn, nn);
        hp = h;
        // |h| < 1 strictly (convex combo) -> i8 quant scale 127, RTN
        hbuf8[(s & 1) ^ 1][ch][colX] = (char)(int)rintf(h * 127.f);
        gcur = gnext;
        block_sync_lds();
      }
    }
    __builtin_amdgcn_s_setprio(0);
    out[(size_t)(b0 + ch) * DIM + colX] = hp;
  } else {
    // ================= PRODUCER (unchanged, bf16) =================
    const int w4 = w - 4;
    const int jg0 = w4 * 32 + c, jg1 = jg0 + 16;
    bf16x8 Bc[3][2][4];
    #pragma unroll
    for (int g = 0; g < 3; ++g)
      #pragma unroll
      for (int Tt = 0; Tt < 2; ++Tt)
        #pragma unroll
        for (int kt = 0; kt < 4; ++kt)
          Bc[g][Tt][kt] = *(const bf16x8*)(wc_bf +
              (g * 128 + w4 * 32 + Tt * 16 + c) * 128 + kt * 32 + q * 8);
    const float fr0 = bc[jg0]       + bhh_s[jg0];
    const float fz0 = bc[128 + jg0] + bhh_s[128 + jg0];
    const float fn0 = bc[256 + jg0];
    const float fr1 = bc[jg1]       + bhh_s[jg1];
    const float fz1 = bc[128 + jg1] + bhh_s[128 + jg1];
    const float fn1 = bc[256 + jg1];

    const int trel = c >> 1, chn = c & 1;   // A-row m = c = 2*trel + chn
    f32x4 xv[8];

    // ---- pre-phase: build chunk 0 into buf 0, then prefetch chunk 1
    {
      const float* xb = x + ((size_t)trel * BATCH + (b0 + chn)) * DIM + q * 8;
      f32x4 xt[8];
      #pragma unroll
      for (int kt = 0; kt < 4; ++kt) {
        xt[2 * kt]     = *(const f32x4*)(xb + kt * 32);
        xt[2 * kt + 1] = *(const f32x4*)(xb + kt * 32 + 4);
      }
      bf16x8 Ax[4];
      #pragma unroll
      for (int kt = 0; kt < 4; ++kt) {
        const f32x4 v0 = xt[2 * kt], v1 = xt[2 * kt + 1];
        bf16x8 a;
        a[0] = f2bf(v0[0]); a[1] = f2bf(v0[1]); a[2] = f2bf(v0[2]); a[3] = f2bf(v0[3]);
        a[4] = f2bf(v1[0]); a[5] = f2bf(v1[1]); a[6] = f2bf(v1[2]); a[7] = f2bf(v1[3]);
        Ax[kt] = a;
      }
      f32x4 ga[2][3];
      #pragma unroll
      for (int g = 0; g < 3; ++g) {
        ga[0][g] = __builtin_amdgcn_mfma_f32_16x16x32_bf16(Ax[0], Bc[g][0][0], zero4, 0, 0, 0);
        ga[1][g] = __builtin_amdgcn_mfma_f32_16x16x32_bf16(Ax[0], Bc[g][1][0], zero4, 0, 0, 0);
      }
      #pragma unroll
      for (int kt = 1; kt < 4; ++kt)
        #pragma unroll
        for (int g = 0; g < 3; ++g) {
          ga[0][g] = __builtin_amdgcn_mfma_f32_16x16x32_bf16(Ax[kt], Bc[g][0][kt], ga[0][g], 0, 0, 0);
          ga[1][g] = __builtin_amdgcn_mfma_f32_16x16x32_bf16(Ax[kt], Bc[g][1][kt], ga[1][g], 0, 0, 0);
        }
      #pragma unroll
      for (int r = 0; r < 4; ++r) {
        f32x4 vA = {ga[0][0][r] + fr0, ga[0][1][r] + fz0, ga[0][2][r] + fn0, 0.f};
        f32x4 vB = {ga[1][0][r] + fr1, ga[1][1][r] + fz1, ga[1][2][r] + fn1, 0.f};
        gi4[0][4 * q + r][jg0] = vA;
        gi4[0][4 * q + r][jg1] = vB;
      }
      const float* xb1 = x + ((size_t)(8 + trel) * BATCH + (b0 + chn)) * DIM + q * 8;
      #pragma unroll
      for (int kt = 0; kt < 4; ++kt) {
        xv[2 * kt]     = *(const f32x4*)(xb1 + kt * 32);
        xv[2 * kt + 1] = *(const f32x4*)(xb1 + kt * 32 + 4);
      }
    }
    __syncthreads();

    for (int cc = 0; cc < NCHUNK; ++cc) {
      const int tc = cc + 1;            // chunk being produced
      bf16x8 Ax[4];
      f32x4 ga[2][3];
      #pragma unroll
      for (int s = 0; s < 8; ++s) {
        if (tc < NCHUNK) {
          // LEVELED f2bf: convert Ax[kt] one per step, just-in-time.
          if (s == 0 || s == 1 || s == 3 || s == 4) {
            const int ck = (s < 2) ? s : s - 1;       // 0,1,2,3
            const f32x4 v0 = xv[2 * ck], v1 = xv[2 * ck + 1];
            bf16x8 a;
            a[0] = f2bf(v0[0]); a[1] = f2bf(v0[1]); a[2] = f2bf(v0[2]); a[3] = f2bf(v0[3]);
            a[4] = f2bf(v1[0]); a[5] = f2bf(v1[1]); a[6] = f2bf(v1[2]); a[7] = f2bf(v1[3]);
            Ax[ck] = a;
          }
          if (s >= 1 && s <= 6) {
            // LEVELED MFMA schedule: 2 (g,kt)-units = 4 MFMAs per step, s=1..6.
            #pragma unroll
            for (int uu = 0; uu < 2; ++uu) {
              const int u = 2 * (s - 1) + uu;
              const int kt = u / 3, g = u % 3;
              if (kt == 0) {
                ga[0][g] = __builtin_amdgcn_mfma_f32_16x16x32_bf16(Ax[0], Bc[g][0][0], zero4, 0, 0, 0);
                ga[1][g] = __builtin_amdgcn_mfma_f32_16x16x32_bf16(Ax[0], Bc[g][1][0], zero4, 0, 0, 0);
              } else {
                ga[0][g] = __builtin_amdgcn_mfma_f32_16x16x32_bf16(Ax[kt], Bc[g][0][kt], ga[0][g], 0, 0, 0);
                ga[1][g] = __builtin_amdgcn_mfma_f32_16x16x32_bf16(Ax[kt], Bc[g][1][kt], ga[1][g], 0, 0, 0);
              }
            }
            if (s == 5 && tc + 1 < NCHUNK) {  // prefetch x for chunk tc+1
              const float* xb = x + ((size_t)((tc + 1) * 8 + trel) * BATCH + (b0 + chn)) * DIM + q * 8;
              #pragma unroll
              for (int kt = 0; kt < 4; ++kt) {
                xv[2 * kt]     = *(const f32x4*)(xb + kt * 32);
                xv[2 * kt + 1] = *(const f32x4*)(xb + kt * 32 + 4);
              }
            }
          } else if (s == 7) {  // bias fold + publish gi for chunk tc
            const int nbuf = tc & 1;
            #pragma unroll
            for (int r = 0; r < 4; ++r) {
              f32x4 vA = {ga[0][0][r] + fr0, ga[0][1][r] + fz0, ga[0][2][r] + fn0, 0.f};
              f32x4 vB = {ga[1][0][r] + fr1, ga[1][1][r] + fz1, ga[1][2][r] + fn1, 0.f};
              gi4[nbuf][4 * q + r][jg0] = vA;
              gi4[nbuf][4 * q + r][jg1] = vB;
            }
          }
        }
        block_sync_lds();
      }
    }
  }
}

// ---------------------------------------------------------------------------
extern "C" void kernel_launch(void* const* d_in, const int* in_sizes, int n_in,
                              void* d_out, int out_size, void* d_ws, size_t ws_size,
                              hipStream_t stream) {
  const float* x    = (const float*)d_in[0];
  const float* W1   = (const float*)d_in[1];
  const float* b1   = (const float*)d_in[2];
  const float* W_ih = (const float*)d_in[3];
  const float* W_hh = (const float*)d_in[4];
  const float* b_ih = (const float*)d_in[5];
  const float* b_hh = (const float*)d_in[6];
  float* out = (float*)d_out;

  char* ws = (char*)d_ws;
  short* wc_bf  = (short*)(ws);             // 384*128 bf16   [0, 98304)
  char*  whh_i8 = (char*) (ws + 98304);     // 384*128 int8   [98304, 147456)
  float* bc     = (float*)(ws + 147456);    // 384 fp32
  float* bhh_s  = (float*)(ws + 148992);    // 384 fp32
  float* dqs    = (float*)(ws + 150528);    // 384 fp32

  prep_kernel<<<dim3(G3), dim3(128), 0, stream>>>(W1, b1, W_ih, W_hh, b_ih, b_hh,
                                                  wc_bf, whh_i8, bc, bhh_s, dqs);
  gru_kernel<<<dim3(BATCH / 2), dim3(512), 0, stream>>>(x, bhh_s, wc_bf, whh_i8, bc, dqs, out);
}